// Round 4
// baseline (467.909 us; speedup 1.0000x reference)
//
#include <hip/hip_runtime.h>
#include <math.h>

#define EPSN 1e-5f

typedef __attribute__((ext_vector_type(8))) short bf16x8;
typedef __attribute__((ext_vector_type(4))) float f32x4;

__device__ __forceinline__ ushort f2bf(float f) {
  unsigned u = __float_as_uint(f);
  unsigned r = (u + 0x7fff + ((u >> 16) & 1)) >> 16;
  return (ushort)r;
}
__device__ __forceinline__ float bf2f(ushort h) {
  return __uint_as_float(((unsigned)h) << 16);
}

// ---------------- block-wide reductions (blockDim.x == 256, 4 waves) --------
__device__ __forceinline__ void breduce2(float& a, float& b, float* lds) {
#pragma unroll
  for (int o = 32; o > 0; o >>= 1) {
    a += __shfl_down(a, o);
    b += __shfl_down(b, o);
  }
  int lane = threadIdx.x & 63, wid = threadIdx.x >> 6;
  __syncthreads();
  if (lane == 0) { lds[wid] = a; lds[4 + wid] = b; }
  __syncthreads();
  a = lds[0] + lds[1] + lds[2] + lds[3];
  b = lds[4] + lds[5] + lds[6] + lds[7];
}

// 4 values, ONE LDS round (for latency-bound phases at 4 waves/CU)
__device__ __forceinline__ void breduce4(float& a, float& b, float& c, float& d,
                                         float* lds) {
#pragma unroll
  for (int o = 32; o > 0; o >>= 1) {
    a += __shfl_down(a, o);
    b += __shfl_down(b, o);
    c += __shfl_down(c, o);
    d += __shfl_down(d, o);
  }
  int lane = threadIdx.x & 63, wid = threadIdx.x >> 6;
  __syncthreads();
  if (lane == 0) {
    lds[wid] = a; lds[4 + wid] = b; lds[8 + wid] = c; lds[12 + wid] = d;
  }
  __syncthreads();
  a = lds[0] + lds[1] + lds[2] + lds[3];
  b = lds[4] + lds[5] + lds[6] + lds[7];
  c = lds[8] + lds[9] + lds[10] + lds[11];
  d = lds[12] + lds[13] + lds[14] + lds[15];
}

__device__ __forceinline__ float breduce_sum(float v, float* lds) {
#pragma unroll
  for (int o = 32; o > 0; o >>= 1) v += __shfl_down(v, o);
  int lane = threadIdx.x & 63, wid = threadIdx.x >> 6;
  __syncthreads();
  if (lane == 0) lds[wid] = v;
  __syncthreads();
  return lds[0] + lds[1] + lds[2] + lds[3];
}

__device__ __forceinline__ float breduce_max(float v, float* lds) {
#pragma unroll
  for (int o = 32; o > 0; o >>= 1) v = fmaxf(v, __shfl_down(v, o));
  int lane = threadIdx.x & 63, wid = threadIdx.x >> 6;
  __syncthreads();
  if (lane == 0) lds[wid] = v;
  __syncthreads();
  return fmaxf(fmaxf(lds[0], lds[1]), fmaxf(lds[2], lds[3]));
}

// ---------------- software grid barrier (256 co-resident blocks) ------------
// ockl-style: arrive = ONE atomic RMW; poll = atomic LOAD (sc1, pipelined at
// the coherence point) — never poll with RMW (R3 lesson: RMW storm = 30us/bar).
__device__ __forceinline__ void gridbar(unsigned* bar) {
  __syncthreads();
  if (threadIdx.x == 0) {
    __threadfence();  // release (buffer_wbl2): block's writes visible
    unsigned old = atomicAdd(bar, 1u);
    if (old != 255u) {
      while (__hip_atomic_load(bar, __ATOMIC_RELAXED, __HIP_MEMORY_SCOPE_AGENT) <
             256u)
        __builtin_amdgcn_s_sleep(8);
    }
    __threadfence();  // acquire (buffer_inv): see other XCDs' writes
  }
  __syncthreads();
}

// ---------------- pre_small: zero barrier counters + diagsum ----------------
__global__ void pre_small(float* __restrict__ diagsum, unsigned* __restrict__ bar) {
  int tid = threadIdx.x;
  diagsum[tid] = 0.f;
  if (tid < 16) bar[tid] = 0u;
}

// ---------------- mega: entire pipeline, 1 launch, 11 grid bars -------------
__global__ __launch_bounds__(256) void mega(
    const float* __restrict__ x, const float* __restrict__ gus,
    const float* __restrict__ wdown, const float* __restrict__ wfuse,
    const float* __restrict__ w3, const float* __restrict__ w5,
    const float* __restrict__ w7,
    ushort* gus_bf, ushort* wdown_bf, ushort* wfuse_bf, ushort* Apk_g,
    ushort* feasH, float* bmean,
    const float* __restrict__ wfc, const float* __restrict__ bfc,
    const float* __restrict__ w0, const float* __restrict__ b0,
    const float* __restrict__ w1, const float* __restrict__ b1,
    const float* __restrict__ w2, const float* __restrict__ b2,
    float* res, ushort* Zt2, ushort* resd,
    float* Tbase,        // aliases: feasRawH (ush) / Apart (fl) / Zt (ush)
    float* rawP,         // aliases: Acomb (ush)
    float* diagsum,
    float* orlt, float* sigt, ushort* orlT,
    float* out, unsigned* bar) {
  int bid = blockIdx.x, tid = threadIdx.x;
  ushort* feasRawH = (ushort*)Tbase;
  float* Apart = Tbase;
  ushort* Zt = (ushort*)Tbase;
  ushort* Acomb = (ushort*)rawP;

  __shared__ union SM {
    ushort xg[9120];                       // sk_mfma staging (18.2 KB)
    struct {
      float sfea[512], zpart[8][32], zz[32], lv[3][32], attb[3][32], tile[32][33];
    } bl;                                  // blend_fc
    float ch[4][324];                      // gram
    float tl[64][33];                      // tconv
  } sm;
  __shared__ float red[16];
  __shared__ float red9[4][9];
  __shared__ float a9s[9];

  // ================= P0: packing/conversions (was pre_kernel) ===============
  for (int vb = bid; vb < 5568; vb += 256) {
    if (vb < 2048) {
      int i = vb * 1024 + tid * 4;
      if (i < 1048576) {
        // gus: permute columns n -> packed r while converting to bf16
        float4 v = *(const float4*)&gus[i];
        int m = i >> 10, n = i & 1023;
        int y = n >> 5, xx = n & 31;           // xx % 4 == 0
        int idxb = ((y >> 1) << 4) + (xx >> 1);
        int py = y & 1;
        ushort2 e0 = {f2bf(v.x), f2bf(v.z)};
        ushort2 e1 = {f2bf(v.y), f2bf(v.w)};
        *(ushort2*)&gus_bf[(size_t)m * 1024 + (py * 2 + 0) * 256 + idxb] = e0;
        *(ushort2*)&gus_bf[(size_t)m * 1024 + (py * 2 + 1) * 256 + idxb] = e1;
      } else {
        const float* src; ushort* dst; int off;
        if (i < 1572864) { src = wdown; dst = wdown_bf; off = i - 1048576; }
        else { src = wfuse; dst = wfuse_bf; off = i - 1572864; }
        float4 v = *(const float4*)&src[off];
        ushort4 o = {f2bf(v.x), f2bf(v.y), f2bf(v.z), f2bf(v.w)};
        *(ushort4*)&dst[off] = o;
      }
    } else if (vb < 2304) {
      int t8 = (vb - 2048) * 256 + tid;
      uint4 z = {0u, 0u, 0u, 0u};
#pragma unroll
      for (int k = 0; k < 4; ++k) *(uint4*)&resd[(size_t)(t8 + k * 65536) * 8] = z;
    } else if (vb < 5056) {
      int i2 = (vb - 2304) * 256 + tid;  // 0..704511
      int g = i2 / 22016;
      int r = i2 - g * 22016;
      int p = r >> 9;
      int r5 = r & 511;
      int quad = r5 >> 7, m16 = (r5 >> 3) & 15, j = r & 7;
      int k = quad * 8 + j, tp = k >> 4, ic = k & 15;
      float val = 0.f;
      if (p < 25) {
        int t = 2 * p + tp;
        if (t < 49) val = w7[(size_t)(g * 16 + m16) * 784 + ic * 49 + t];
      } else if (p < 38) {
        int t = 2 * (p - 25) + tp;
        if (t < 25) val = w5[(size_t)(g * 16 + m16) * 400 + ic * 25 + t];
      } else {
        int t = 2 * (p - 38) + tp;
        if (t < 9) val = w3[(size_t)(g * 16 + m16) * 144 + ic * 9 + t];
      }
      Apk_g[i2] = f2bf(val);
    } else {
      int j = (vb - 5056) * 256 + tid;  // < 131072
      uint4 z = {0u, 0u, 0u, 0u};
      ((uint4*)Acomb)[j] = z;
    }
  }
  gridbar(&bar[0]);

  // ================= P1: sk_mfma (vb = bid, exactly 256) ====================
  {
    int g = bid >> 3, sl = bid & 7, y0 = sl * 4;
    for (int i = tid; i < 4560; i += 256) ((uint*)sm.xg)[i] = 0u;
    __syncthreads();
    for (int i = tid; i < 5120; i += 256) {
      int lr = i >> 9, ic = (i >> 5) & 15, xc = i & 31;
      int y = y0 + lr - 3;
      if ((unsigned)y < 32u)
        sm.xg[(lr * 38 + xc + 3) * 24 + ic] =
            f2bf(x[(size_t)(g * 16 + ic) * 1024 + y * 32 + xc]);
    }
    __syncthreads();
    int wv = tid >> 6, lane = tid & 63, quad = lane >> 4, m16 = lane & 15;
    int qh = (quad & 1) * 8, tp = quad >> 1;
    const ushort* Ag = Apk_g + (size_t)g * 22016;
    f32x4 acc[2][3] = {};
#pragma unroll
    for (int p = 0; p < 25; ++p) {  // k7 (br 2)
      bf16x8 af = *(const bf16x8*)&Ag[(p * 4 + quad) * 128 + m16 * 8];
      int t = 2 * p + tp;
      if (t > 48) t = 48;
      int ky = t / 7, kx = t - ky * 7;
#pragma unroll
      for (int ti = 0; ti < 2; ++ti) {
        int T = wv + ti * 4, tl = T >> 1, x0c = (T & 1) * 16;
        bf16x8 bf = *(const bf16x8*)&sm.xg[((tl + ky) * 38 + x0c + m16 + kx) * 24 + qh];
        acc[ti][2] = __builtin_amdgcn_mfma_f32_16x16x32_bf16(af, bf, acc[ti][2], 0, 0, 0);
      }
    }
#pragma unroll
    for (int p = 0; p < 13; ++p) {  // k5 (br 1)
      bf16x8 af = *(const bf16x8*)&Ag[((p + 25) * 4 + quad) * 128 + m16 * 8];
      int t = 2 * p + tp;
      if (t > 24) t = 24;
      int ky = t / 5, kx = t - ky * 5;
#pragma unroll
      for (int ti = 0; ti < 2; ++ti) {
        int T = wv + ti * 4, tl = T >> 1, x0c = (T & 1) * 16;
        bf16x8 bf =
            *(const bf16x8*)&sm.xg[((tl + ky + 1) * 38 + x0c + m16 + kx + 1) * 24 + qh];
        acc[ti][1] = __builtin_amdgcn_mfma_f32_16x16x32_bf16(af, bf, acc[ti][1], 0, 0, 0);
      }
    }
#pragma unroll
    for (int p = 0; p < 5; ++p) {  // k3 (br 0)
      bf16x8 af = *(const bf16x8*)&Ag[((p + 38) * 4 + quad) * 128 + m16 * 8];
      int t = 2 * p + tp;
      if (t > 8) t = 8;
      int ky = t / 3, kx = t - ky * 3;
#pragma unroll
      for (int ti = 0; ti < 2; ++ti) {
        int T = wv + ti * 4, tl = T >> 1, x0c = (T & 1) * 16;
        bf16x8 bf =
            *(const bf16x8*)&sm.xg[((tl + ky + 2) * 38 + x0c + m16 + kx + 2) * 24 + qh];
        acc[ti][0] = __builtin_amdgcn_mfma_f32_16x16x32_bf16(af, bf, acc[ti][0], 0, 0, 0);
      }
    }
    int cb = g * 16 + quad * 4;
#pragma unroll
    for (int ti = 0; ti < 2; ++ti) {
      int T = wv + ti * 4, tl = T >> 1, x0c = (T & 1) * 16;
      int pos = (y0 + tl) * 32 + x0c + m16;
#pragma unroll
      for (int br = 0; br < 3; ++br)
#pragma unroll
        for (int r = 0; r < 4; ++r)
          feasRawH[(size_t)(br * 512 + cb + r) * 1024 + pos] = f2bf(acc[ti][br][r]);
    }
  }
  gridbar(&bar[1]);

  // ================= P2: sk_norm (1536 channels, paired: 3 iters) ===========
  for (int it = 0; it < 3; ++it) {
    int mcA = bid + it * 512, mcB = mcA + 256;
    float vA[4], vB[4];
    {
      ushort4 hA = *(const ushort4*)&feasRawH[(size_t)mcA * 1024 + tid * 4];
      ushort4 hB = *(const ushort4*)&feasRawH[(size_t)mcB * 1024 + tid * 4];
      vA[0] = bf2f(hA.x); vA[1] = bf2f(hA.y); vA[2] = bf2f(hA.z); vA[3] = bf2f(hA.w);
      vB[0] = bf2f(hB.x); vB[1] = bf2f(hB.y); vB[2] = bf2f(hB.z); vB[3] = bf2f(hB.w);
    }
    float sA = 0.f, ssA = 0.f, sB = 0.f, ssB = 0.f;
#pragma unroll
    for (int r = 0; r < 4; ++r) {
      sA += vA[r]; ssA += vA[r] * vA[r];
      sB += vB[r]; ssB += vB[r] * vB[r];
    }
    breduce4(sA, ssA, sB, ssB, red);
    float meanA = sA * (1.f / 1024.f);
    float invA = rsqrtf(ssA * (1.f / 1024.f) - meanA * meanA + EPSN);
    float meanB = sB * (1.f / 1024.f);
    float invB = rsqrtf(ssB * (1.f / 1024.f) - meanB * meanB + EPSN);
    float rsA = 0.f, rsB = 0.f;
    ushort4 oA, oB;
#pragma unroll
    for (int r = 0; r < 4; ++r) {
      float tA = (vA[r] - meanA) * invA;
      tA = tA > 0.f ? tA : 0.f;
      ((ushort*)&oA)[r] = f2bf(tA);
      rsA += tA;
      float tB = (vB[r] - meanB) * invB;
      tB = tB > 0.f ? tB : 0.f;
      ((ushort*)&oB)[r] = f2bf(tB);
      rsB += tB;
    }
    *(ushort4*)&feasH[(size_t)mcA * 1024 + tid * 4] = oA;
    *(ushort4*)&feasH[(size_t)mcB * 1024 + tid * 4] = oB;
    breduce2(rsA, rsB, red);
    if (tid == 0) {
      bmean[mcA] = rsA * (1.f / 1024.f);
      bmean[mcB] = rsB * (1.f / 1024.f);
    }
  }
  gridbar(&bar[2]);

  // ================= P3: blend_fc (512 virtual blocks) ======================
  for (int vb = bid; vb < 512; vb += 256) {
    int pb = (vb & 31) * 32, cb = (vb >> 5) * 32;
    for (int c = tid; c < 512; c += 256)
      sm.bl.sfea[c] = bmean[c] + bmean[512 + c] + bmean[1024 + c];
    __syncthreads();
    {
      int j = tid & 31, seg = tid >> 5;
      float p = 0.f;
      for (int c = seg * 64; c < seg * 64 + 64; ++c)
        p += sm.bl.sfea[c] * wfc[j * 512 + c];
      sm.bl.zpart[seg][j] = p;
    }
    __syncthreads();
    if (tid < 32) {
      float d = bfc[tid];
#pragma unroll
      for (int s = 0; s < 8; ++s) d += sm.bl.zpart[s][tid];
      sm.bl.zz[tid] = d;
    }
    __syncthreads();
    if (tid < 96) {
      int m = tid >> 5, cl = tid & 31;
      const float* wm = (m == 0) ? w0 : (m == 1) ? w1 : w2;
      const float* bm = (m == 0) ? b0 : (m == 1) ? b1 : b2;
      float l = bm[cb + cl];
#pragma unroll
      for (int j = 0; j < 32; ++j) l += sm.bl.zz[j] * wm[(cb + cl) * 32 + j];
      sm.bl.lv[m][cl] = l;
    }
    __syncthreads();
    if (tid < 32) {
      float l0 = sm.bl.lv[0][tid], l1 = sm.bl.lv[1][tid], l2 = sm.bl.lv[2][tid];
      float mx = fmaxf(l0, fmaxf(l1, l2));
      float e0 = expf(l0 - mx), e1 = expf(l1 - mx), e2 = expf(l2 - mx);
      float inv = 1.f / (e0 + e1 + e2);
      sm.bl.attb[0][tid] = e0 * inv;
      sm.bl.attb[1][tid] = e1 * inv;
      sm.bl.attb[2][tid] = e2 * inv;
    }
    __syncthreads();
    int tx = tid & 31, ty = tid >> 5;
    int pos = pb + tx;
    int yy = pos >> 5, xx = pos & 31;
    int ki0 = (yy + 1) & 1, pi0 = (yy + 1 - ki0) >> 1;
    int kj0 = (xx + 1) & 1, pj0 = (xx + 1 - kj0) >> 1;
#pragma unroll
    for (int r = 0; r < 4; ++r) {
      int cl = ty + r * 8;
      int c = cb + cl;
      float v = bf2f(feasH[(size_t)c * 1024 + pos]) * sm.bl.attb[0][cl] +
                bf2f(feasH[(size_t)(512 + c) * 1024 + pos]) * sm.bl.attb[1][cl] +
                bf2f(feasH[(size_t)(1024 + c) * 1024 + pos]) * sm.bl.attb[2][cl];
      res[c * 1024 + pos] = v;
      sm.bl.tile[cl][tx] = v;
      ushort bv16 = f2bf(v);
#pragma unroll
      for (int ai = 0; ai < 2; ++ai) {
        int ki = ki0 + 2 * ai, pi = pi0 - ai;
        if ((unsigned)pi >= 16u) continue;
#pragma unroll
        for (int aj = 0; aj < 2; ++aj) {
          int kj = kj0 + 2 * aj, pj = pj0 - aj;
          if ((unsigned)pj >= 16u) continue;
          resd[((size_t)(ki * 4 + kj) << 17) + (size_t)c * 256 + pi * 16 + pj] = bv16;
        }
      }
    }
    __syncthreads();
#pragma unroll
    for (int r = 0; r < 4; ++r) {
      int pl = ty + r * 8;
      Zt2[(size_t)(pb + pl) * 1024 + 512 + cb + tx] = f2bf(sm.bl.tile[tx][pl]);
    }
    __syncthreads();  // protect sm.bl reuse across vb iterations
  }
  gridbar(&bar[3]);

  // ================= P4: gram (320 virtual blocks) ==========================
  for (int vb = bid; vb < 320; vb += 256) {
    const int PBT[10] = {0, 0, 0, 0, 1, 1, 1, 2, 2, 3};
    const int QBT[10] = {0, 1, 2, 3, 1, 2, 3, 2, 3, 3};
    int pid = vb % 10, kc = vb / 10;
    int pb = PBT[pid] * 64, qb = QBT[pid] * 64;
    int tx = tid & 15, ty = tid >> 4;
    for (int i = tid; i < 4 * 324; i += 256) ((float*)sm.ch)[i] = 0.f;
    int pi = (pb + ty * 4) >> 4, pj = (pb + ty * 4) & 15;
    int qi = (qb + tx * 4) >> 4, qj = (qb + tx * 4) & 15;
    int lane = tid & 63, wv = tid >> 6;
    int sr = lane >> 2, sc = (lane & 3) * 4;
    float acc[4][4] = {};
    for (int c0 = kc * 16; c0 < kc * 16 + 16; c0 += 4) {
      __syncthreads();
      {
        const float* src = res + (size_t)(c0 + wv) * 1024 + (2 * sr) * 32 + 2 * sc;
        float4 r0a = *(const float4*)src;
        float4 r0b = *(const float4*)(src + 4);
        float4 r1a = *(const float4*)(src + 32);
        float4 r1b = *(const float4*)(src + 36);
        float* dst = &sm.ch[wv][(sr + 1) * 18 + sc + 1];
        dst[0] = 0.25f * (r0a.x + r0a.y + r1a.x + r1a.y);
        dst[1] = 0.25f * (r0a.z + r0a.w + r1a.z + r1a.w);
        dst[2] = 0.25f * (r0b.x + r0b.y + r1b.x + r1b.y);
        dst[3] = 0.25f * (r0b.z + r0b.w + r1b.z + r1b.w);
      }
      __syncthreads();
#pragma unroll
      for (int cc = 0; cc < 4; ++cc) {
        float ps[3][6], qs[3][6];
#pragma unroll
        for (int u = 0; u < 3; ++u) {
          const float* pr = &sm.ch[cc][(pi + u) * 18 + pj];
          const float* qr = &sm.ch[cc][(qi + u) * 18 + qj];
#pragma unroll
          for (int t = 0; t < 6; ++t) { ps[u][t] = pr[t]; qs[u][t] = qr[t]; }
        }
#pragma unroll
        for (int u = 0; u < 3; ++u)
#pragma unroll
          for (int v = 0; v < 3; ++v)
#pragma unroll
            for (int i = 0; i < 4; ++i)
#pragma unroll
              for (int j = 0; j < 4; ++j)
                acc[i][j] += ps[u][v + i] * qs[u][v + j];
      }
    }
#pragma unroll
    for (int i = 0; i < 4; ++i) {
      float4 o4 = {acc[i][0], acc[i][1], acc[i][2], acc[i][3]};
      *(float4*)&Apart[(size_t)kc * 65536 + (pb + ty * 4 + i) * 256 + qb + tx * 4] = o4;
    }
    if (pb != qb) {
#pragma unroll
      for (int j = 0; j < 4; ++j) {
        float4 o4 = {acc[0][j], acc[1][j], acc[2][j], acc[3][j]};
        *(float4*)&Apart[(size_t)kc * 65536 + (qb + tx * 4 + j) * 256 + pb + ty * 4] = o4;
      }
    } else if (tx == ty) {
#pragma unroll
      for (int i = 0; i < 4; ++i) atomicAdd(&diagsum[pb + tx * 4 + i], acc[i][i]);
    }
    __syncthreads();
  }
  gridbar(&bar[4]);

  // ================= P5: attn_soft4 (256 virtual blocks) ====================
  {
    int q = bid, t = tid;
    float d = diagsum[t];
    float s = 0.f;
#pragma unroll
    for (int k = 0; k < 32; ++k) s += Apart[(size_t)k * 65536 + q * 256 + t];
    float invn = 10.f / fmaxf(sqrtf(fmaxf(d, 0.f)), 1e-4f);
    float v = s * invn;
    float mx = breduce_max(v, red);
    float e = expf(v - mx);
    float smv = breduce_sum(e, red);
    ushort val = f2bf(e / smv);
    int qi = q >> 4, qj = q & 15;
#pragma unroll
    for (int ki = 0; ki < 4; ++ki) {
      int y = 2 * qi + ki - 1;
      if ((unsigned)y >= 32u) continue;
#pragma unroll
      for (int kj = 0; kj < 4; ++kj) {
        int x2 = 2 * qj + kj - 1;
        if ((unsigned)x2 >= 32u) continue;
        int cls = (y & 1) * 2 + (x2 & 1);
        int idx = ((y >> 1) << 4) + (x2 >> 1);
        int seg = ((ki >> 1) << 1) + (kj >> 1);
        Acomb[(size_t)(cls * 256 + idx) * 1024 + seg * 256 + t] = val;
      }
    }
  }
  gridbar(&bar[5]);

  // ================= P6: tconv2 (256 virtual blocks) ========================
  {
    int wv = tid >> 6, lane = tid & 63, quad = lane >> 4, m16 = lane & 15;
    int nb = (bid & 15) * 32;
    int mb = (bid >> 4) * 64;
    int cls = bid >> 6;
    int py = cls >> 1, px = cls & 1;
    int row0 = mb + wv * 16 + m16;
    const ushort* Ap = Acomb + (size_t)row0 * 1024 + quad * 8;
    f32x4 ac0 = {0.f, 0.f, 0.f, 0.f}, ac1 = ac0;
#pragma unroll
    for (int sg = 0; sg < 4; ++sg) {
      int ki = 2 * (sg >> 1) + 1 - py;
      int kj = 2 * (sg & 1) + 1 - px;
      const ushort* Bp =
          resd + ((size_t)(ki * 4 + kj) << 17) + (size_t)(nb + m16) * 256 + quad * 8;
      const ushort* As = Ap + sg * 256;
#pragma unroll 4
      for (int k0 = 0; k0 < 256; k0 += 32) {
        bf16x8 af = *(const bf16x8*)(As + k0);
        bf16x8 b0 = *(const bf16x8*)(Bp + k0);
        bf16x8 b1 = *(const bf16x8*)(Bp + 16 * 256 + k0);
        ac0 = __builtin_amdgcn_mfma_f32_16x16x32_bf16(af, b0, ac0, 0, 0, 0);
        ac1 = __builtin_amdgcn_mfma_f32_16x16x32_bf16(af, b1, ac1, 0, 0, 0);
      }
    }
    int rloc0 = wv * 16 + quad * 4;
    f32x4 accs[2] = {ac0, ac1};
#pragma unroll
    for (int nt = 0; nt < 2; ++nt) {
      int c = nb + nt * 16 + m16;
#pragma unroll
      for (int r = 0; r < 4; ++r) {
        int rl = rloc0 + r;
        int idx = (mb + rl) & 255;
        int y = ((idx >> 4) << 1) + py;
        int x2 = ((idx & 15) << 1) + px;
        int n = y * 32 + x2;
        float v = accs[nt][r] * 0.25f;
        orlt[n * 512 + c] = v;
        sigt[n * 512 + c] = 1.f / (1.f + expf(-v));
        sm.tl[rl][nt * 16 + m16] = v;
      }
    }
    __syncthreads();
    int r_l = tid & 63;
#pragma unroll
    for (int k = 0; k < 8; ++k) {
      int c_l = (tid >> 6) + k * 4;
      orlT[(size_t)(nb + c_l) * 1024 + mb + r_l] = f2bf(sm.tl[r_l][c_l]);
    }
  }
  gridbar(&bar[6]);

  // ================= P7: gus_csa (1152 virtual blocks) ======================
  for (int vb = bid; vb < 1152; vb += 256) {
    if (vb < 128) {
      const int K = 1024;
      int wv = tid >> 6, lane = tid & 63;
      int quad = lane >> 4, m16 = lane & 15;
      int nb = (vb & 7) * 64, mb = (vb >> 3) * 64;
      const ushort* Ap = gus_bf + (size_t)(mb + wv * 16 + m16) * K + quad * 8;
      const ushort* Bp = orlT + (size_t)(nb + m16) * K + quad * 8;
      f32x4 ac0 = {0.f, 0.f, 0.f, 0.f}, ac1 = ac0, ac2 = ac0, ac3 = ac0;
#pragma unroll 4
      for (int k0 = 0; k0 < K; k0 += 32) {
        bf16x8 af = *(const bf16x8*)(Ap + k0);
        bf16x8 b0 = *(const bf16x8*)(Bp + k0);
        bf16x8 b1 = *(const bf16x8*)(Bp + (size_t)16 * K + k0);
        bf16x8 b2 = *(const bf16x8*)(Bp + (size_t)32 * K + k0);
        bf16x8 b3 = *(const bf16x8*)(Bp + (size_t)48 * K + k0);
        ac0 = __builtin_amdgcn_mfma_f32_16x16x32_bf16(af, b0, ac0, 0, 0, 0);
        ac1 = __builtin_amdgcn_mfma_f32_16x16x32_bf16(af, b1, ac1, 0, 0, 0);
        ac2 = __builtin_amdgcn_mfma_f32_16x16x32_bf16(af, b2, ac2, 0, 0, 0);
        ac3 = __builtin_amdgcn_mfma_f32_16x16x32_bf16(af, b3, ac3, 0, 0, 0);
      }
      int row = mb + wv * 16 + quad * 4;
      f32x4 accs[4] = {ac0, ac1, ac2, ac3};
#pragma unroll
      for (int nt = 0; nt < 4; ++nt) {
        int c = nb + nt * 16 + m16;
#pragma unroll
        for (int r = 0; r < 4; ++r) {
          int p = row + r;
          int pos = ((p & 1) << 9) + c;
          int kk = p >> 1;
          Zt[(size_t)pos * 1024 + kk] = f2bf(accs[nt][r]);
        }
      }
    } else {
      int n = vb - 128;
      int ny = n >> 5, nx = n & 31;
      int c2 = tid * 2;
      int lane = tid & 63, wid = tid >> 6;
      float2 ctr = *(const float2*)&sigt[n * 512 + c2];
      float part[9];
#pragma unroll
      for (int u = 0; u < 3; ++u) {
        int yy = ny + u - 1;
#pragma unroll
        for (int v = 0; v < 3; ++v) {
          int xx = nx + v - 1;
          float2 nb2 = {0.f, 0.f};
          if ((unsigned)yy < 32u && (unsigned)xx < 32u)
            nb2 = *(const float2*)&sigt[(yy * 32 + xx) * 512 + c2];
          part[u * 3 + v] = ctr.x * nb2.x + ctr.y * nb2.y;
        }
      }
#pragma unroll
      for (int t = 0; t < 9; ++t)
#pragma unroll
        for (int o = 32; o > 0; o >>= 1) part[t] += __shfl_down(part[t], o);
      __syncthreads();  // protect red9 reuse across vb iterations
      if (lane == 0)
#pragma unroll
        for (int t = 0; t < 9; ++t) red9[wid][t] = part[t];
      __syncthreads();
      if (tid == 0) {
        float a[9];
#pragma unroll
        for (int t = 0; t < 9; ++t)
          a[t] = (red9[0][t] + red9[1][t] + red9[2][t] + red9[3][t]) * (1.f / 512.f);
        float mx = a[0];
#pragma unroll
        for (int t = 1; t < 9; ++t) mx = fmaxf(mx, a[t]);
        float sum = 0.f;
#pragma unroll
        for (int t = 0; t < 9; ++t) { a[t] = expf(a[t] - mx); sum += a[t]; }
        float inv = 1.f / sum;
#pragma unroll
        for (int t = 0; t < 9; ++t) a9s[t] = a[t] * inv;
      }
      __syncthreads();
      float2 acc = {0.f, 0.f};
#pragma unroll
      for (int u = 0; u < 3; ++u) {
        int yy = ny + u - 1;
#pragma unroll
        for (int v = 0; v < 3; ++v) {
          int xx = nx + v - 1;
          if ((unsigned)yy < 32u && (unsigned)xx < 32u) {
            float w = a9s[u * 3 + v];
            float2 ov = *(const float2*)&orlt[(yy * 32 + xx) * 512 + c2];
            acc.x += w * ov.x;
            acc.y += w * ov.y;
          }
        }
      }
      int kk = 512 + (n >> 1);
      int pos0 = ((n & 1) << 9) + c2;
      Zt[(size_t)pos0 * 1024 + kk] = f2bf(acc.x);
      Zt[(size_t)(pos0 + 1) * 1024 + kk] = f2bf(acc.y);
    }
  }
  gridbar(&bar[7]);

  // ================= P8: GEMM wdown (256 virtual blocks) ====================
  {
    const int KF = 1024;
    int wv = tid >> 6, lane = tid & 63;
    int quad = lane >> 4, m16 = lane & 15;
    int nb = (bid & 15) * 64, mb = ((bid >> 4) & 7) * 64, kh = bid >> 7;
    const ushort* Ap = wdown_bf + (size_t)(mb + wv * 16 + m16) * KF + kh * 512 + quad * 8;
    const ushort* Bp = Zt + (size_t)(nb + m16) * KF + kh * 512 + quad * 8;
    f32x4 ac0 = {0.f, 0.f, 0.f, 0.f}, ac1 = ac0, ac2 = ac0, ac3 = ac0;
#pragma unroll 4
    for (int k0 = 0; k0 < 512; k0 += 32) {
      bf16x8 af = *(const bf16x8*)(Ap + k0);
      bf16x8 b0 = *(const bf16x8*)(Bp + k0);
      bf16x8 b1 = *(const bf16x8*)(Bp + (size_t)16 * KF + k0);
      bf16x8 b2 = *(const bf16x8*)(Bp + (size_t)32 * KF + k0);
      bf16x8 b3 = *(const bf16x8*)(Bp + (size_t)48 * KF + k0);
      ac0 = __builtin_amdgcn_mfma_f32_16x16x32_bf16(af, b0, ac0, 0, 0, 0);
      ac1 = __builtin_amdgcn_mfma_f32_16x16x32_bf16(af, b1, ac1, 0, 0, 0);
      ac2 = __builtin_amdgcn_mfma_f32_16x16x32_bf16(af, b2, ac2, 0, 0, 0);
      ac3 = __builtin_amdgcn_mfma_f32_16x16x32_bf16(af, b3, ac3, 0, 0, 0);
    }
    int row = mb + wv * 16 + quad * 4;
    float* C = rawP + (size_t)kh * 524288;
    f32x4 accs[4] = {ac0, ac1, ac2, ac3};
#pragma unroll
    for (int nt = 0; nt < 4; ++nt)
#pragma unroll
      for (int r = 0; r < 4; ++r)
        C[(size_t)(row + r) * 1024 + nb + nt * 16 + m16] = accs[nt][r];
  }
  gridbar(&bar[8]);

  // ================= P9: norm_down2 (512 channels, paired) ==================
  {
    int c0 = bid, c1 = bid + 256;
    float vA[4], vB[4];
    float sA = 0.f, ssA = 0.f, sB = 0.f, ssB = 0.f;
#pragma unroll
    for (int r = 0; r < 4; ++r) {
      int iA = c0 * 1024 + tid + r * 256;
      int iB = c1 * 1024 + tid + r * 256;
      vA[r] = rawP[iA] + rawP[524288 + iA];
      vB[r] = rawP[iB] + rawP[524288 + iB];
      sA += vA[r]; ssA += vA[r] * vA[r];
      sB += vB[r]; ssB += vB[r] * vB[r];
    }
    breduce4(sA, ssA, sB, ssB, red);
    float meanA = sA * (1.f / 1024.f);
    float invA = rsqrtf(ssA * (1.f / 1024.f) - meanA * meanA + EPSN);
    float meanB = sB * (1.f / 1024.f);
    float invB = rsqrtf(ssB * (1.f / 1024.f) - meanB * meanB + EPSN);
#pragma unroll
    for (int r = 0; r < 4; ++r) {
      float tA = (vA[r] - meanA) * invA;
      tA = tA >= 0.f ? tA : 0.2f * tA;
      Zt2[(size_t)(tid + r * 256) * 1024 + c0] = f2bf(tA);
      float tB = (vB[r] - meanB) * invB;
      tB = tB >= 0.f ? tB : 0.2f * tB;
      Zt2[(size_t)(tid + r * 256) * 1024 + c1] = f2bf(tB);
    }
  }
  gridbar(&bar[9]);

  // ================= P10: GEMM wfuse (256 virtual blocks) ===================
  {
    const int KF = 1024;
    int wv = tid >> 6, lane = tid & 63;
    int quad = lane >> 4, m16 = lane & 15;
    int nb = (bid & 15) * 64, mb = ((bid >> 4) & 7) * 64, kh = bid >> 7;
    const ushort* Ap = wfuse_bf + (size_t)(mb + wv * 16 + m16) * KF + kh * 512 + quad * 8;
    const ushort* Bp = (const ushort*)Zt2 + (size_t)(nb + m16) * KF + kh * 512 + quad * 8;
    f32x4 ac0 = {0.f, 0.f, 0.f, 0.f}, ac1 = ac0, ac2 = ac0, ac3 = ac0;
#pragma unroll 4
    for (int k0 = 0; k0 < 512; k0 += 32) {
      bf16x8 af = *(const bf16x8*)(Ap + k0);
      bf16x8 b0 = *(const bf16x8*)(Bp + k0);
      bf16x8 b1 = *(const bf16x8*)(Bp + (size_t)16 * KF + k0);
      bf16x8 b2 = *(const bf16x8*)(Bp + (size_t)32 * KF + k0);
      bf16x8 b3 = *(const bf16x8*)(Bp + (size_t)48 * KF + k0);
      ac0 = __builtin_amdgcn_mfma_f32_16x16x32_bf16(af, b0, ac0, 0, 0, 0);
      ac1 = __builtin_amdgcn_mfma_f32_16x16x32_bf16(af, b1, ac1, 0, 0, 0);
      ac2 = __builtin_amdgcn_mfma_f32_16x16x32_bf16(af, b2, ac2, 0, 0, 0);
      ac3 = __builtin_amdgcn_mfma_f32_16x16x32_bf16(af, b3, ac3, 0, 0, 0);
    }
    int row = mb + wv * 16 + quad * 4;
    float* C = rawP + (size_t)kh * 524288;
    f32x4 accs[4] = {ac0, ac1, ac2, ac3};
#pragma unroll
    for (int nt = 0; nt < 4; ++nt)
#pragma unroll
      for (int r = 0; r < 4; ++r)
        C[(size_t)(row + r) * 1024 + nb + nt * 16 + m16] = accs[nt][r];
  }
  gridbar(&bar[10]);

  // ================= P11: norm_leaky2 -> out (512 channels, paired) =========
  {
    int c0 = bid, c1 = bid + 256;
    float vA[4], vB[4];
    float sA = 0.f, ssA = 0.f, sB = 0.f, ssB = 0.f;
#pragma unroll
    for (int r = 0; r < 4; ++r) {
      int iA = c0 * 1024 + tid + r * 256;
      int iB = c1 * 1024 + tid + r * 256;
      vA[r] = rawP[iA] + rawP[524288 + iA];
      vB[r] = rawP[iB] + rawP[524288 + iB];
      sA += vA[r]; ssA += vA[r] * vA[r];
      sB += vB[r]; ssB += vB[r] * vB[r];
    }
    breduce4(sA, ssA, sB, ssB, red);
    float meanA = sA * (1.f / 1024.f);
    float invA = rsqrtf(ssA * (1.f / 1024.f) - meanA * meanA + EPSN);
    float meanB = sB * (1.f / 1024.f);
    float invB = rsqrtf(ssB * (1.f / 1024.f) - meanB * meanB + EPSN);
#pragma unroll
    for (int r = 0; r < 4; ++r) {
      float tA = (vA[r] - meanA) * invA;
      out[c0 * 1024 + tid + r * 256] = tA >= 0.f ? tA : 0.2f * tA;
      float tB = (vB[r] - meanB) * invB;
      out[c1 * 1024 + tid + r * 256] = tB >= 0.f ? tB : 0.2f * tB;
    }
  }
}

// ---------------- host launch ------------------------------------------------
extern "C" void kernel_launch(void* const* d_in, const int* in_sizes, int n_in,
                              void* d_out, int out_size, void* d_ws, size_t ws_size,
                              hipStream_t stream) {
  const float* x = (const float*)d_in[0];
  const float* gus = (const float*)d_in[1];
  const float* w3 = (const float*)d_in[2];
  const float* w5 = (const float*)d_in[4];
  const float* w7 = (const float*)d_in[6];
  const float* wfc = (const float*)d_in[8];
  const float* bfc = (const float*)d_in[9];
  const float* w0 = (const float*)d_in[10];
  const float* b0 = (const float*)d_in[11];
  const float* w1 = (const float*)d_in[12];
  const float* b1 = (const float*)d_in[13];
  const float* w2 = (const float*)d_in[14];
  const float* b2 = (const float*)d_in[15];
  const float* wdown = (const float*)d_in[16];
  const float* wfuse = (const float*)d_in[17];

  float* ws = (float*)d_ws;
  ushort* feasH = (ushort*)ws;           // 1572864 ush (dead after blend)
  float* rawP = ws + 786432;             // 2x524288 fl partials / Acomb alias
  float* bmean = ws + 1835008;           // 1536
  float* res = bmean + 1536;             // 524288
  float* Zt2f = res + 524288;            // 524288 fl
  ushort* Zt2 = (ushort*)Zt2f;
  float* T = Zt2f + 524288;              // 2097152 (feasRawH/Apart/Zt alias)
  float* orlt = T + 2097152;             // 524288
  float* sigt = orlt + 524288;           // 524288
  ushort* orlT = (ushort*)(sigt + 524288);        // 262144 fl
  ushort* gus_bf = (ushort*)(sigt + 819200);      // 524288 fl
  ushort* wdown_bf = (ushort*)(sigt + 1343488);   // 262144 fl
  ushort* wfuse_bf = (ushort*)(sigt + 1605632);   // 262144 fl
  ushort* resd = (ushort*)(sigt + 1867776);       // 1048576 fl
  ushort* Apk_g = (ushort*)(sigt + 2916352);      // 704512 ush
  float* diagsum = sigt + 3268608;                // 256 fl
  unsigned* bar = (unsigned*)(diagsum + 256);     // 16 u32 barrier counters

  pre_small<<<1, 256, 0, stream>>>(diagsum, bar);
  mega<<<256, 256, 0, stream>>>(x, gus, wdown, wfuse, w3, w5, w7, gus_bf,
                                wdown_bf, wfuse_bf, Apk_g, feasH, bmean, wfc,
                                bfc, w0, b0, w1, b1, w2, b2, res, Zt2, resd, T,
                                rawP, diagsum, orlt, sigt, orlT, (float*)d_out,
                                bar);
}

// Round 6
// 235.254 us; speedup vs baseline: 1.9890x; 1.9890x over previous
//
#include <hip/hip_runtime.h>
#include <math.h>

#define EPSN 1e-5f

typedef __attribute__((ext_vector_type(8))) short bf16x8;
typedef __attribute__((ext_vector_type(4))) float f32x4;

__device__ __forceinline__ ushort f2bf(float f) {
  unsigned u = __float_as_uint(f);
  unsigned r = (u + 0x7fff + ((u >> 16) & 1)) >> 16;
  return (ushort)r;
}
__device__ __forceinline__ float bf2f(ushort h) {
  return __uint_as_float(((unsigned)h) << 16);
}

// ---------------- block-wide reductions (blockDim.x == 256, 4 waves) --------
__device__ __forceinline__ void breduce2(float& a, float& b, float* lds) {
#pragma unroll
  for (int o = 32; o > 0; o >>= 1) {
    a += __shfl_down(a, o);
    b += __shfl_down(b, o);
  }
  int lane = threadIdx.x & 63, wid = threadIdx.x >> 6;
  __syncthreads();
  if (lane == 0) { lds[wid] = a; lds[4 + wid] = b; }
  __syncthreads();
  a = lds[0] + lds[1] + lds[2] + lds[3];
  b = lds[4] + lds[5] + lds[6] + lds[7];
}

// 4 values, ONE LDS round (latency-bound norm phases)
__device__ __forceinline__ void breduce4(float& a, float& b, float& c, float& d,
                                         float* lds) {
#pragma unroll
  for (int o = 32; o > 0; o >>= 1) {
    a += __shfl_down(a, o);
    b += __shfl_down(b, o);
    c += __shfl_down(c, o);
    d += __shfl_down(d, o);
  }
  int lane = threadIdx.x & 63, wid = threadIdx.x >> 6;
  __syncthreads();
  if (lane == 0) {
    lds[wid] = a; lds[4 + wid] = b; lds[8 + wid] = c; lds[12 + wid] = d;
  }
  __syncthreads();
  a = lds[0] + lds[1] + lds[2] + lds[3];
  b = lds[4] + lds[5] + lds[6] + lds[7];
  c = lds[8] + lds[9] + lds[10] + lds[11];
  d = lds[12] + lds[13] + lds[14] + lds[15];
}

__device__ __forceinline__ float breduce_sum(float v, float* lds) {
#pragma unroll
  for (int o = 32; o > 0; o >>= 1) v += __shfl_down(v, o);
  int lane = threadIdx.x & 63, wid = threadIdx.x >> 6;
  __syncthreads();
  if (lane == 0) lds[wid] = v;
  __syncthreads();
  return lds[0] + lds[1] + lds[2] + lds[3];
}

__device__ __forceinline__ float breduce_max(float v, float* lds) {
#pragma unroll
  for (int o = 32; o > 0; o >>= 1) v = fmaxf(v, __shfl_down(v, o));
  int lane = threadIdx.x & 63, wid = threadIdx.x >> 6;
  __syncthreads();
  if (lane == 0) lds[wid] = v;
  __syncthreads();
  return fmaxf(fmaxf(lds[0], lds[1]), fmaxf(lds[2], lds[3]));
}

// ---------------- K1: SKConv MFMA (in-LDS A-pack) + concurrent pre work -----
// bid<256: SK blocks — pack own group's 22016-elem A panel into LDS (44 KB),
// stage x into LDS, MFMA. bid>=256: aux blocks do gus/wdown/wfuse bf16
// converts + resd/Acomb/diagsum zeroing concurrently on idle CUs.
__global__ __launch_bounds__(256) void sk_pre(
    const float* __restrict__ x, const float* __restrict__ gus,
    const float* __restrict__ wdown, const float* __restrict__ wfuse,
    const float* __restrict__ w3, const float* __restrict__ w5,
    const float* __restrict__ w7,
    ushort* __restrict__ gus_bf, ushort* __restrict__ wdown_bf,
    ushort* __restrict__ wfuse_bf, ushort* __restrict__ resd,
    ushort* __restrict__ AcombZ, float* __restrict__ diagsum,
    ushort* __restrict__ feasRawH) {
  int bid = blockIdx.x, tid = threadIdx.x;
  if (bid >= 256) {
    int vb = bid - 256;
    if (vb < 2048) {
      int i = vb * 1024 + tid * 4;
      if (i < 1048576) {
        // gus: permute columns n -> packed r while converting to bf16
        // r = cls*256 + (y>>1)*16 + (x>>1), cls=(y&1)*2+(x&1)
        float4 v = *(const float4*)&gus[i];
        int m = i >> 10, n = i & 1023;
        int y = n >> 5, xx = n & 31;  // xx % 4 == 0
        int idxb = ((y >> 1) << 4) + (xx >> 1);
        int py = y & 1;
        ushort2 e0 = {f2bf(v.x), f2bf(v.z)};
        ushort2 e1 = {f2bf(v.y), f2bf(v.w)};
        *(ushort2*)&gus_bf[(size_t)m * 1024 + (py * 2 + 0) * 256 + idxb] = e0;
        *(ushort2*)&gus_bf[(size_t)m * 1024 + (py * 2 + 1) * 256 + idxb] = e1;
      } else {
        const float* src; ushort* dst; int off;
        if (i < 1572864) { src = wdown; dst = wdown_bf; off = i - 1048576; }
        else { src = wfuse; dst = wfuse_bf; off = i - 1572864; }
        float4 v = *(const float4*)&src[off];
        ushort4 o = {f2bf(v.x), f2bf(v.y), f2bf(v.z), f2bf(v.w)};
        *(ushort4*)&dst[off] = o;
      }
    } else if (vb < 2304) {
      if (vb == 2048) diagsum[tid] = 0.f;
      int t8 = (vb - 2048) * 256 + tid;
      uint4 z = {0u, 0u, 0u, 0u};
#pragma unroll
      for (int k = 0; k < 4; ++k) *(uint4*)&resd[(size_t)(t8 + k * 65536) * 8] = z;
    } else {
      int j = (vb - 2304) * 256 + tid;  // < 131072
      uint4 z = {0u, 0u, 0u, 0u};
      ((uint4*)AcombZ)[j] = z;
    }
    return;
  }
  // ---- SK block ----
  __shared__ ushort apk[22016];        // 44 KB: this group's packed A panel
  __shared__ ushort xg[10 * 38 * 24];  // 18.2 KB: [lr][cx][ic pad24]
  int g = bid >> 3, sl = bid & 7, y0 = sl * 4;
  for (int i = tid; i < 4560; i += 256) ((uint*)xg)[i] = 0u;
  __syncthreads();
  for (int i = tid; i < 5120; i += 256) {
    int lr = i >> 9, ic = (i >> 5) & 15, xc = i & 31;
    int y = y0 + lr - 3;
    if ((unsigned)y < 32u)
      xg[(lr * 38 + xc + 3) * 24 + ic] =
          f2bf(x[(size_t)(g * 16 + ic) * 1024 + y * 32 + xc]);
  }
  // pack A panel (22016 = 86*256): same layout as old pre_kernel Apk_g
  for (int i = tid; i < 22016; i += 256) {
    int p = i >> 9;
    int r5 = i & 511;
    int quad = r5 >> 7, m16v = (r5 >> 3) & 15, j = i & 7;
    int k = quad * 8 + j, tp = k >> 4, ic = k & 15;
    float val = 0.f;
    if (p < 25) {
      int t = 2 * p + tp;
      if (t < 49) val = w7[(size_t)(g * 16 + m16v) * 784 + ic * 49 + t];
    } else if (p < 38) {
      int t = 2 * (p - 25) + tp;
      if (t < 25) val = w5[(size_t)(g * 16 + m16v) * 400 + ic * 25 + t];
    } else {
      int t = 2 * (p - 38) + tp;
      if (t < 9) val = w3[(size_t)(g * 16 + m16v) * 144 + ic * 9 + t];
    }
    apk[i] = f2bf(val);
  }
  __syncthreads();
  int wv = tid >> 6, lane = tid & 63, quad = lane >> 4, m16 = lane & 15;
  int qh = (quad & 1) * 8, tp = quad >> 1;
  f32x4 acc[2][3] = {};
#pragma unroll
  for (int p = 0; p < 25; ++p) {  // k7 (br 2)
    bf16x8 af = *(const bf16x8*)&apk[(p * 4 + quad) * 128 + m16 * 8];
    int t = 2 * p + tp;
    if (t > 48) t = 48;
    int ky = t / 7, kx = t - ky * 7;
#pragma unroll
    for (int ti = 0; ti < 2; ++ti) {
      int T = wv + ti * 4, tl = T >> 1, x0c = (T & 1) * 16;
      bf16x8 bf = *(const bf16x8*)&xg[((tl + ky) * 38 + x0c + m16 + kx) * 24 + qh];
      acc[ti][2] = __builtin_amdgcn_mfma_f32_16x16x32_bf16(af, bf, acc[ti][2], 0, 0, 0);
    }
  }
#pragma unroll
  for (int p = 0; p < 13; ++p) {  // k5 (br 1)
    bf16x8 af = *(const bf16x8*)&apk[((p + 25) * 4 + quad) * 128 + m16 * 8];
    int t = 2 * p + tp;
    if (t > 24) t = 24;
    int ky = t / 5, kx = t - ky * 5;
#pragma unroll
    for (int ti = 0; ti < 2; ++ti) {
      int T = wv + ti * 4, tl = T >> 1, x0c = (T & 1) * 16;
      bf16x8 bf =
          *(const bf16x8*)&xg[((tl + ky + 1) * 38 + x0c + m16 + kx + 1) * 24 + qh];
      acc[ti][1] = __builtin_amdgcn_mfma_f32_16x16x32_bf16(af, bf, acc[ti][1], 0, 0, 0);
    }
  }
#pragma unroll
  for (int p = 0; p < 5; ++p) {  // k3 (br 0)
    bf16x8 af = *(const bf16x8*)&apk[((p + 38) * 4 + quad) * 128 + m16 * 8];
    int t = 2 * p + tp;
    if (t > 8) t = 8;
    int ky = t / 3, kx = t - ky * 3;
#pragma unroll
    for (int ti = 0; ti < 2; ++ti) {
      int T = wv + ti * 4, tl = T >> 1, x0c = (T & 1) * 16;
      bf16x8 bf =
          *(const bf16x8*)&xg[((tl + ky + 2) * 38 + x0c + m16 + kx + 2) * 24 + qh];
      acc[ti][0] = __builtin_amdgcn_mfma_f32_16x16x32_bf16(af, bf, acc[ti][0], 0, 0, 0);
    }
  }
  int cb = g * 16 + quad * 4;
#pragma unroll
  for (int ti = 0; ti < 2; ++ti) {
    int T = wv + ti * 4, tl = T >> 1, x0c = (T & 1) * 16;
    int pos = (y0 + tl) * 32 + x0c + m16;
#pragma unroll
    for (int br = 0; br < 3; ++br)
#pragma unroll
      for (int r = 0; r < 4; ++r)
        feasRawH[(size_t)(br * 512 + cb + r) * 1024 + pos] = f2bf(acc[ti][br][r]);
  }
}

// ---------------- InstanceNorm + ReLU + branch-mean, 2 channels/block -------
__global__ __launch_bounds__(256) void sk_norm2(const ushort* __restrict__ rawH,
                                                ushort* __restrict__ feasH,
                                                float* __restrict__ bmean) {
  __shared__ float red[16];
  int tid = threadIdx.x;
  int mcA = blockIdx.x, mcB = mcA + 768;
  float vA[4], vB[4];
  {
    ushort4 hA = *(const ushort4*)&rawH[(size_t)mcA * 1024 + tid * 4];
    ushort4 hB = *(const ushort4*)&rawH[(size_t)mcB * 1024 + tid * 4];
    vA[0] = bf2f(hA.x); vA[1] = bf2f(hA.y); vA[2] = bf2f(hA.z); vA[3] = bf2f(hA.w);
    vB[0] = bf2f(hB.x); vB[1] = bf2f(hB.y); vB[2] = bf2f(hB.z); vB[3] = bf2f(hB.w);
  }
  float sA = 0.f, ssA = 0.f, sB = 0.f, ssB = 0.f;
#pragma unroll
  for (int r = 0; r < 4; ++r) {
    sA += vA[r]; ssA += vA[r] * vA[r];
    sB += vB[r]; ssB += vB[r] * vB[r];
  }
  breduce4(sA, ssA, sB, ssB, red);
  float meanA = sA * (1.f / 1024.f);
  float invA = rsqrtf(ssA * (1.f / 1024.f) - meanA * meanA + EPSN);
  float meanB = sB * (1.f / 1024.f);
  float invB = rsqrtf(ssB * (1.f / 1024.f) - meanB * meanB + EPSN);
  float rsA = 0.f, rsB = 0.f;
  ushort4 oA, oB;
#pragma unroll
  for (int r = 0; r < 4; ++r) {
    float tA = (vA[r] - meanA) * invA;
    tA = tA > 0.f ? tA : 0.f;
    ((ushort*)&oA)[r] = f2bf(tA);
    rsA += tA;
    float tB = (vB[r] - meanB) * invB;
    tB = tB > 0.f ? tB : 0.f;
    ((ushort*)&oB)[r] = f2bf(tB);
    rsB += tB;
  }
  *(ushort4*)&feasH[(size_t)mcA * 1024 + tid * 4] = oA;
  *(ushort4*)&feasH[(size_t)mcB * 1024 + tid * 4] = oB;
  breduce2(rsA, rsB, red);
  if (tid == 0) {
    bmean[mcA] = rsA * (1.f / 1024.f);
    bmean[mcB] = rsB * (1.f / 1024.f);
  }
}

// ---------------- blend + FC-attention; reads bf16 feas ---------------------
__global__ __launch_bounds__(256) void blend_fc(
    const ushort* __restrict__ feasH, const float* __restrict__ bmean,
    const float* __restrict__ wfc, const float* __restrict__ bfc,
    const float* __restrict__ w0, const float* __restrict__ b0,
    const float* __restrict__ w1, const float* __restrict__ b1,
    const float* __restrict__ w2, const float* __restrict__ b2,
    float* __restrict__ res, ushort* __restrict__ Zt2,
    ushort* __restrict__ resd) {
  __shared__ float sfea[512];
  __shared__ float zpart[8][32];
  __shared__ float zz[32];
  __shared__ float lv[3][32];
  __shared__ float attb[3][32];
  __shared__ float tile[32][33];
  int tid = threadIdx.x;
  int pb = blockIdx.x * 32, cb = blockIdx.y * 32;
  for (int c = tid; c < 512; c += 256)
    sfea[c] = bmean[c] + bmean[512 + c] + bmean[1024 + c];
  __syncthreads();
  {
    int j = tid & 31, seg = tid >> 5;
    float p = 0.f;
    for (int c = seg * 64; c < seg * 64 + 64; ++c) p += sfea[c] * wfc[j * 512 + c];
    zpart[seg][j] = p;
  }
  __syncthreads();
  if (tid < 32) {
    float d = bfc[tid];
#pragma unroll
    for (int s = 0; s < 8; ++s) d += zpart[s][tid];
    zz[tid] = d;
  }
  __syncthreads();
  if (tid < 96) {
    int m = tid >> 5, cl = tid & 31;
    const float* wm = (m == 0) ? w0 : (m == 1) ? w1 : w2;
    const float* bm = (m == 0) ? b0 : (m == 1) ? b1 : b2;
    float l = bm[cb + cl];
#pragma unroll
    for (int j = 0; j < 32; ++j) l += zz[j] * wm[(cb + cl) * 32 + j];
    lv[m][cl] = l;
  }
  __syncthreads();
  if (tid < 32) {
    float l0 = lv[0][tid], l1 = lv[1][tid], l2 = lv[2][tid];
    float mx = fmaxf(l0, fmaxf(l1, l2));
    float e0 = expf(l0 - mx), e1 = expf(l1 - mx), e2 = expf(l2 - mx);
    float inv = 1.f / (e0 + e1 + e2);
    attb[0][tid] = e0 * inv; attb[1][tid] = e1 * inv; attb[2][tid] = e2 * inv;
  }
  __syncthreads();
  int tx = tid & 31, ty = tid >> 5;
  int pos = pb + tx;
  int yy = pos >> 5, xx = pos & 31;
  int ki0 = (yy + 1) & 1, pi0 = (yy + 1 - ki0) >> 1;
  int kj0 = (xx + 1) & 1, pj0 = (xx + 1 - kj0) >> 1;
#pragma unroll
  for (int r = 0; r < 4; ++r) {
    int cl = ty + r * 8;
    int c = cb + cl;
    float v = bf2f(feasH[(size_t)c * 1024 + pos]) * attb[0][cl] +
              bf2f(feasH[(size_t)(512 + c) * 1024 + pos]) * attb[1][cl] +
              bf2f(feasH[(size_t)(1024 + c) * 1024 + pos]) * attb[2][cl];
    res[c * 1024 + pos] = v;
    tile[cl][tx] = v;
    ushort bv16 = f2bf(v);
#pragma unroll
    for (int ai = 0; ai < 2; ++ai) {
      int ki = ki0 + 2 * ai, pi = pi0 - ai;
      if ((unsigned)pi >= 16u) continue;
#pragma unroll
      for (int aj = 0; aj < 2; ++aj) {
        int kj = kj0 + 2 * aj, pj = pj0 - aj;
        if ((unsigned)pj >= 16u) continue;
        resd[((size_t)(ki * 4 + kj) << 17) + (size_t)c * 256 + pi * 16 + pj] = bv16;
      }
    }
  }
  __syncthreads();
#pragma unroll
  for (int r = 0; r < 4; ++r) {
    int pl = ty + r * 8;
    Zt2[(size_t)(pb + pl) * 1024 + 512 + cb + tx] = f2bf(tile[tx][pl]);
  }
}

// ---------------- Gram split-K partials, SYMMETRIC (upper pairs only) -------
__global__ __launch_bounds__(256) void gram_part2(const float* __restrict__ res,
                                                  float* __restrict__ Apart,
                                                  float* __restrict__ diagsum) {
  __shared__ float ch[4][324];
  const int PBT[10] = {0, 0, 0, 0, 1, 1, 1, 2, 2, 3};
  const int QBT[10] = {0, 1, 2, 3, 1, 2, 3, 2, 3, 3};
  int tid = threadIdx.x;
  int pid = blockIdx.x;
  int pb = PBT[pid] * 64, qb = QBT[pid] * 64;
  int kc = blockIdx.z;
  int tx = tid & 15, ty = tid >> 4;
  for (int i = tid; i < 4 * 324; i += 256) ((float*)ch)[i] = 0.f;
  int pi = (pb + ty * 4) >> 4, pj = (pb + ty * 4) & 15;
  int qi = (qb + tx * 4) >> 4, qj = (qb + tx * 4) & 15;
  int lane = tid & 63, wv = tid >> 6;
  int sr = lane >> 2, sc = (lane & 3) * 4;
  float acc[4][4] = {};
  for (int c0 = kc * 16; c0 < kc * 16 + 16; c0 += 4) {
    __syncthreads();
    {
      const float* src = res + (size_t)(c0 + wv) * 1024 + (2 * sr) * 32 + 2 * sc;
      float4 r0a = *(const float4*)src;
      float4 r0b = *(const float4*)(src + 4);
      float4 r1a = *(const float4*)(src + 32);
      float4 r1b = *(const float4*)(src + 36);
      float* dst = &ch[wv][(sr + 1) * 18 + sc + 1];
      dst[0] = 0.25f * (r0a.x + r0a.y + r1a.x + r1a.y);
      dst[1] = 0.25f * (r0a.z + r0a.w + r1a.z + r1a.w);
      dst[2] = 0.25f * (r0b.x + r0b.y + r1b.x + r1b.y);
      dst[3] = 0.25f * (r0b.z + r0b.w + r1b.z + r1b.w);
    }
    __syncthreads();
#pragma unroll
    for (int cc = 0; cc < 4; ++cc) {
      float ps[3][6], qs[3][6];
#pragma unroll
      for (int u = 0; u < 3; ++u) {
        const float* pr = &ch[cc][(pi + u) * 18 + pj];
        const float* qr = &ch[cc][(qi + u) * 18 + qj];
#pragma unroll
        for (int t = 0; t < 6; ++t) { ps[u][t] = pr[t]; qs[u][t] = qr[t]; }
      }
#pragma unroll
      for (int u = 0; u < 3; ++u)
#pragma unroll
        for (int v = 0; v < 3; ++v)
#pragma unroll
          for (int i = 0; i < 4; ++i)
#pragma unroll
            for (int j = 0; j < 4; ++j)
              acc[i][j] += ps[u][v + i] * qs[u][v + j];
    }
  }
#pragma unroll
  for (int i = 0; i < 4; ++i) {
    float4 o4 = {acc[i][0], acc[i][1], acc[i][2], acc[i][3]};
    *(float4*)&Apart[(size_t)kc * 65536 + (pb + ty * 4 + i) * 256 + qb + tx * 4] = o4;
  }
  if (pb != qb) {
#pragma unroll
    for (int j = 0; j < 4; ++j) {
      float4 o4 = {acc[0][j], acc[1][j], acc[2][j], acc[3][j]};
      *(float4*)&Apart[(size_t)kc * 65536 + (qb + tx * 4 + j) * 256 + pb + ty * 4] = o4;
    }
  } else if (tx == ty) {
#pragma unroll
    for (int i = 0; i < 4; ++i) atomicAdd(&diagsum[pb + tx * 4 + i], acc[i][i]);
  }
}

// ---------------- softmax + diag norm -> Acomb (class-packed rows) ----------
__global__ __launch_bounds__(256) void attn_soft4(const float* __restrict__ Apart,
                                                  const float* __restrict__ diagsum,
                                                  ushort* __restrict__ Acomb) {
  __shared__ float red[8];
  int q = blockIdx.x, t = threadIdx.x;
  float d = diagsum[t];
  float s = 0.f;
#pragma unroll
  for (int k = 0; k < 32; ++k) s += Apart[(size_t)k * 65536 + q * 256 + t];
  float invn = 10.f / fmaxf(sqrtf(fmaxf(d, 0.f)), 1e-4f);
  float v = s * invn;
  float mx = breduce_max(v, red);
  float e = expf(v - mx);
  float sm = breduce_sum(e, red);
  ushort val = f2bf(e / sm);
  int qi = q >> 4, qj = q & 15;
#pragma unroll
  for (int ki = 0; ki < 4; ++ki) {
    int y = 2 * qi + ki - 1;
    if ((unsigned)y >= 32u) continue;
#pragma unroll
    for (int kj = 0; kj < 4; ++kj) {
      int x = 2 * qj + kj - 1;
      if ((unsigned)x >= 32u) continue;
      int cls = (y & 1) * 2 + (x & 1);
      int idx = ((y >> 1) << 4) + (x >> 1);
      int seg = ((ki >> 1) << 1) + (kj >> 1);
      Acomb[(size_t)(cls * 256 + idx) * 1024 + seg * 256 + t] = val;
    }
  }
}

// ---------------- fused tconv+tcomb: K=4x256 GEMM over class-shared taps ----
__global__ __launch_bounds__(256) void tconv2(const ushort* __restrict__ Acomb,
                                              const ushort* __restrict__ resd,
                                              float* __restrict__ orlt,
                                              float* __restrict__ sigt,
                                              ushort* __restrict__ orlT) {
  __shared__ float tl[64][33];
  int tid = threadIdx.x;
  int wv = tid >> 6, lane = tid & 63, quad = lane >> 4, m16 = lane & 15;
  int nb = blockIdx.x * 32;   // channel tile
  int mb = blockIdx.y * 64;   // packed-row tile
  int cls = blockIdx.y >> 2;
  int py = cls >> 1, px = cls & 1;
  int row0 = mb + wv * 16 + m16;
  const ushort* Ap = Acomb + (size_t)row0 * 1024 + quad * 8;
  f32x4 ac0 = {0.f, 0.f, 0.f, 0.f}, ac1 = ac0;
#pragma unroll
  for (int sg = 0; sg < 4; ++sg) {
    int ki = 2 * (sg >> 1) + 1 - py;
    int kj = 2 * (sg & 1) + 1 - px;
    const ushort* Bp =
        resd + ((size_t)(ki * 4 + kj) << 17) + (size_t)(nb + m16) * 256 + quad * 8;
    const ushort* As = Ap + sg * 256;
#pragma unroll 4
    for (int k0 = 0; k0 < 256; k0 += 32) {
      bf16x8 af = *(const bf16x8*)(As + k0);
      bf16x8 b0 = *(const bf16x8*)(Bp + k0);
      bf16x8 b1 = *(const bf16x8*)(Bp + 16 * 256 + k0);
      ac0 = __builtin_amdgcn_mfma_f32_16x16x32_bf16(af, b0, ac0, 0, 0, 0);
      ac1 = __builtin_amdgcn_mfma_f32_16x16x32_bf16(af, b1, ac1, 0, 0, 0);
    }
  }
  int rloc0 = wv * 16 + quad * 4;
  f32x4 accs[2] = {ac0, ac1};
#pragma unroll
  for (int nt = 0; nt < 2; ++nt) {
    int c = nb + nt * 16 + m16;
#pragma unroll
    for (int r = 0; r < 4; ++r) {
      int rl = rloc0 + r;
      int idx = (mb + rl) & 255;
      int y = ((idx >> 4) << 1) + py;
      int x = ((idx & 15) << 1) + px;
      int n = y * 32 + x;
      float v = accs[nt][r] * 0.25f;
      orlt[n * 512 + c] = v;
      sigt[n * 512 + c] = 1.f / (1.f + expf(-v));
      tl[rl][nt * 16 + m16] = v;
    }
  }
  __syncthreads();
  int r_l = tid & 63;
#pragma unroll
  for (int k = 0; k < 8; ++k) {
    int c_l = (tid >> 6) + k * 4;
    orlT[(size_t)(nb + c_l) * 1024 + mb + r_l] = f2bf(tl[r_l][c_l]);
  }
}

// ---------------- merged: gus GEMM (blocks 0..127) + CSA (128..1151) --------
__global__ __launch_bounds__(256) void gus_csa(
    const ushort* __restrict__ gus_bf, const ushort* __restrict__ orlT,
    const float* __restrict__ sigt, const float* __restrict__ orlt,
    ushort* __restrict__ Zt) {
  __shared__ float red9[4][9];
  __shared__ float a9s[9];
  int tid = threadIdx.x;
  if (blockIdx.x < 128) {
    const int K = 1024;
    int wv = tid >> 6, lane = tid & 63;
    int quad = lane >> 4, m16 = lane & 15;
    int nb = (blockIdx.x & 7) * 64, mb = (blockIdx.x >> 3) * 64;
    const ushort* Ap = gus_bf + (size_t)(mb + wv * 16 + m16) * K + quad * 8;
    const ushort* Bp = orlT + (size_t)(nb + m16) * K + quad * 8;
    f32x4 ac0 = {0.f, 0.f, 0.f, 0.f}, ac1 = ac0, ac2 = ac0, ac3 = ac0;
#pragma unroll 4
    for (int k0 = 0; k0 < K; k0 += 32) {
      bf16x8 af = *(const bf16x8*)(Ap + k0);
      bf16x8 b0 = *(const bf16x8*)(Bp + k0);
      bf16x8 b1 = *(const bf16x8*)(Bp + (size_t)16 * K + k0);
      bf16x8 b2 = *(const bf16x8*)(Bp + (size_t)32 * K + k0);
      bf16x8 b3 = *(const bf16x8*)(Bp + (size_t)48 * K + k0);
      ac0 = __builtin_amdgcn_mfma_f32_16x16x32_bf16(af, b0, ac0, 0, 0, 0);
      ac1 = __builtin_amdgcn_mfma_f32_16x16x32_bf16(af, b1, ac1, 0, 0, 0);
      ac2 = __builtin_amdgcn_mfma_f32_16x16x32_bf16(af, b2, ac2, 0, 0, 0);
      ac3 = __builtin_amdgcn_mfma_f32_16x16x32_bf16(af, b3, ac3, 0, 0, 0);
    }
    int row = mb + wv * 16 + quad * 4;
    f32x4 accs[4] = {ac0, ac1, ac2, ac3};
#pragma unroll
    for (int nt = 0; nt < 4; ++nt) {
      int c = nb + nt * 16 + m16;
#pragma unroll
      for (int r = 0; r < 4; ++r) {
        int p = row + r;
        int pos = ((p & 1) << 9) + c;
        int kk = p >> 1;
        Zt[(size_t)pos * 1024 + kk] = f2bf(accs[nt][r]);
      }
    }
    return;
  }
  int n = blockIdx.x - 128;
  int ny = n >> 5, nx = n & 31;
  int c2 = tid * 2;
  int lane = tid & 63, wid = tid >> 6;
  float2 ctr = *(const float2*)&sigt[n * 512 + c2];
  float part[9];
#pragma unroll
  for (int u = 0; u < 3; ++u) {
    int yy = ny + u - 1;
#pragma unroll
    for (int v = 0; v < 3; ++v) {
      int xx = nx + v - 1;
      float2 nb2 = {0.f, 0.f};
      if ((unsigned)yy < 32u && (unsigned)xx < 32u)
        nb2 = *(const float2*)&sigt[(yy * 32 + xx) * 512 + c2];
      part[u * 3 + v] = ctr.x * nb2.x + ctr.y * nb2.y;
    }
  }
#pragma unroll
  for (int t = 0; t < 9; ++t)
#pragma unroll
    for (int o = 32; o > 0; o >>= 1) part[t] += __shfl_down(part[t], o);
  if (lane == 0)
#pragma unroll
    for (int t = 0; t < 9; ++t) red9[wid][t] = part[t];
  __syncthreads();
  if (tid == 0) {
    float a[9];
#pragma unroll
    for (int t = 0; t < 9; ++t)
      a[t] = (red9[0][t] + red9[1][t] + red9[2][t] + red9[3][t]) * (1.f / 512.f);
    float mx = a[0];
#pragma unroll
    for (int t = 1; t < 9; ++t) mx = fmaxf(mx, a[t]);
    float sum = 0.f;
#pragma unroll
    for (int t = 0; t < 9; ++t) { a[t] = expf(a[t] - mx); sum += a[t]; }
    float inv = 1.f / sum;
#pragma unroll
    for (int t = 0; t < 9; ++t) a9s[t] = a[t] * inv;
  }
  __syncthreads();
  float2 acc = {0.f, 0.f};
#pragma unroll
  for (int u = 0; u < 3; ++u) {
    int yy = ny + u - 1;
#pragma unroll
    for (int v = 0; v < 3; ++v) {
      int xx = nx + v - 1;
      if ((unsigned)yy < 32u && (unsigned)xx < 32u) {
        float w = a9s[u * 3 + v];
        float2 ov = *(const float2*)&orlt[(yy * 32 + xx) * 512 + c2];
        acc.x += w * ov.x;
        acc.y += w * ov.y;
      }
    }
  }
  int kk = 512 + (n >> 1);
  int pos0 = ((n & 1) << 9) + c2;
  Zt[(size_t)pos0 * 1024 + kk] = f2bf(acc.x);
  Zt[(size_t)(pos0 + 1) * 1024 + kk] = f2bf(acc.y);
}

// ---------------- K-split bf16 MFMA GEMM: 2 halves -> 2 fp32 partials -------
__global__ __launch_bounds__(256) void mfma_gemm_ks(const ushort* __restrict__ A,
                                                    const ushort* __restrict__ Bt,
                                                    float* __restrict__ Cp,
                                                    int N) {
  const int KF = 1024;
  int tid = threadIdx.x;
  int wv = tid >> 6, lane = tid & 63;
  int quad = lane >> 4, m16 = lane & 15;
  int nb = blockIdx.x * 64, mb = blockIdx.y * 64;
  int kh = blockIdx.z;
  const ushort* Ap = A + (size_t)(mb + wv * 16 + m16) * KF + kh * 512 + quad * 8;
  const ushort* Bp = Bt + (size_t)(nb + m16) * KF + kh * 512 + quad * 8;
  f32x4 ac0 = {0.f, 0.f, 0.f, 0.f}, ac1 = ac0, ac2 = ac0, ac3 = ac0;
#pragma unroll 4
  for (int k0 = 0; k0 < 512; k0 += 32) {
    bf16x8 af = *(const bf16x8*)(Ap + k0);
    bf16x8 b0 = *(const bf16x8*)(Bp + k0);
    bf16x8 b1 = *(const bf16x8*)(Bp + (size_t)16 * KF + k0);
    bf16x8 b2 = *(const bf16x8*)(Bp + (size_t)32 * KF + k0);
    bf16x8 b3 = *(const bf16x8*)(Bp + (size_t)48 * KF + k0);
    ac0 = __builtin_amdgcn_mfma_f32_16x16x32_bf16(af, b0, ac0, 0, 0, 0);
    ac1 = __builtin_amdgcn_mfma_f32_16x16x32_bf16(af, b1, ac1, 0, 0, 0);
    ac2 = __builtin_amdgcn_mfma_f32_16x16x32_bf16(af, b2, ac2, 0, 0, 0);
    ac3 = __builtin_amdgcn_mfma_f32_16x16x32_bf16(af, b3, ac3, 0, 0, 0);
  }
  int row = mb + wv * 16 + quad * 4;
  float* C = Cp + (size_t)kh * 524288;
  f32x4 accs[4] = {ac0, ac1, ac2, ac3};
#pragma unroll
  for (int nt = 0; nt < 4; ++nt)
#pragma unroll
    for (int r = 0; r < 4; ++r)
      C[(size_t)(row + r) * N + nb + nt * 16 + m16] = accs[nt][r];
}

// ---------------- InstanceNorm + LeakyReLU, 2 channels/block -> Zt2 bf16 ----
__global__ __launch_bounds__(256) void norm_down2p(const float* __restrict__ ra,
                                                   ushort* __restrict__ Zt2) {
  __shared__ float red[16];
  int tid = threadIdx.x;
  int c0 = blockIdx.x, c1 = c0 + 256;
  float vA[4], vB[4];
  float sA = 0.f, ssA = 0.f, sB = 0.f, ssB = 0.f;
#pragma unroll
  for (int r = 0; r < 4; ++r) {
    int iA = c0 * 1024 + tid + r * 256;
    int iB = c1 * 1024 + tid + r * 256;
    vA[r] = ra[iA] + ra[524288 + iA];
    vB[r] = ra[iB] + ra[524288 + iB];
    sA += vA[r]; ssA += vA[r] * vA[r];
    sB += vB[r]; ssB += vB[r] * vB[r];
  }
  breduce4(sA, ssA, sB, ssB, red);
  float meanA = sA * (1.f / 1024.f);
  float invA = rsqrtf(ssA * (1.f / 1024.f) - meanA * meanA + EPSN);
  float meanB = sB * (1.f / 1024.f);
  float invB = rsqrtf(ssB * (1.f / 1024.f) - meanB * meanB + EPSN);
#pragma unroll
  for (int r = 0; r < 4; ++r) {
    float tA = (vA[r] - meanA) * invA;
    tA = tA >= 0.f ? tA : 0.2f * tA;
    Zt2[(size_t)(tid + r * 256) * 1024 + c0] = f2bf(tA);
    float tB = (vB[r] - meanB) * invB;
    tB = tB >= 0.f ? tB : 0.2f * tB;
    Zt2[(size_t)(tid + r * 256) * 1024 + c1] = f2bf(tB);
  }
}

// ---------------- final InstanceNorm + LeakyReLU, 2 channels/block ----------
__global__ __launch_bounds__(256) void norm_leaky2p(const float* __restrict__ ra,
                                                    float* __restrict__ out) {
  __shared__ float red[16];
  int tid = threadIdx.x;
  int c0 = blockIdx.x, c1 = c0 + 256;
  float vA[4], vB[4];
  float sA = 0.f, ssA = 0.f, sB = 0.f, ssB = 0.f;
#pragma unroll
  for (int r = 0; r < 4; ++r) {
    int iA = c0 * 1024 + tid + r * 256;
    int iB = c1 * 1024 + tid + r * 256;
    vA[r] = ra[iA] + ra[524288 + iA];
    vB[r] = ra[iB] + ra[524288 + iB];
    sA += vA[r]; ssA += vA[r] * vA[r];
    sB += vB[r]; ssB += vB[r] * vB[r];
  }
  breduce4(sA, ssA, sB, ssB, red);
  float meanA = sA * (1.f / 1024.f);
  float invA = rsqrtf(ssA * (1.f / 1024.f) - meanA * meanA + EPSN);
  float meanB = sB * (1.f / 1024.f);
  float invB = rsqrtf(ssB * (1.f / 1024.f) - meanB * meanB + EPSN);
#pragma unroll
  for (int r = 0; r < 4; ++r) {
    float tA = (vA[r] - meanA) * invA;
    out[c0 * 1024 + tid + r * 256] = tA >= 0.f ? tA : 0.2f * tA;
    float tB = (vB[r] - meanB) * invB;
    out[c1 * 1024 + tid + r * 256] = tB >= 0.f ? tB : 0.2f * tB;
  }
}

// ---------------- host launch ------------------------------------------------
extern "C" void kernel_launch(void* const* d_in, const int* in_sizes, int n_in,
                              void* d_out, int out_size, void* d_ws, size_t ws_size,
                              hipStream_t stream) {
  const float* x = (const float*)d_in[0];
  const float* gus = (const float*)d_in[1];
  const float* w3 = (const float*)d_in[2];
  const float* w5 = (const float*)d_in[4];
  const float* w7 = (const float*)d_in[6];
  const float* wfc = (const float*)d_in[8];
  const float* bfc = (const float*)d_in[9];
  const float* w0 = (const float*)d_in[10];
  const float* b0 = (const float*)d_in[11];
  const float* w1 = (const float*)d_in[12];
  const float* b1 = (const float*)d_in[13];
  const float* w2 = (const float*)d_in[14];
  const float* b2 = (const float*)d_in[15];
  const float* wdown = (const float*)d_in[16];
  const float* wfuse = (const float*)d_in[17];

  float* ws = (float*)d_ws;
  ushort* feasH = (ushort*)ws;           // 1572864 ush (dead after blend)
  float* rawP = ws + 786432;             // 2x524288 fl partials / Acomb alias
  ushort* Acomb = (ushort*)rawP;
  float* bmean = ws + 1835008;           // 1536
  float* res = bmean + 1536;             // 524288
  float* Zt2f = res + 524288;            // 524288 fl
  ushort* Zt2 = (ushort*)Zt2f;
  float* T = Zt2f + 524288;              // 2097152 (feasRawH/Apart/Zt alias)
  ushort* feasRawH = (ushort*)T;
  float* Apart = T;
  ushort* Zt = (ushort*)T;
  float* orlt = T + 2097152;             // 524288
  float* sigt = orlt + 524288;           // 524288
  ushort* orlT = (ushort*)(sigt + 524288);        // 262144 fl
  ushort* gus_bf = (ushort*)(sigt + 819200);      // 524288 fl
  ushort* wdown_bf = (ushort*)(sigt + 1343488);   // 262144 fl
  ushort* wfuse_bf = (ushort*)(sigt + 1605632);   // 262144 fl
  ushort* resd = (ushort*)(sigt + 1867776);       // 1048576 fl
  float* diagsum = sigt + 3268608;                // 256 fl

  sk_pre<<<3072, 256, 0, stream>>>(x, gus, wdown, wfuse, w3, w5, w7, gus_bf,
                                   wdown_bf, wfuse_bf, resd, Acomb, diagsum,
                                   feasRawH);
  sk_norm2<<<768, 256, 0, stream>>>(feasRawH, feasH, bmean);
  blend_fc<<<dim3(32, 16), 256, 0, stream>>>(feasH, bmean, wfc, bfc, w0, b0, w1,
                                             b1, w2, b2, res, Zt2, resd);
  gram_part2<<<dim3(10, 1, 32), 256, 0, stream>>>(res, Apart, diagsum);
  attn_soft4<<<256, 256, 0, stream>>>(Apart, diagsum, Acomb);
  tconv2<<<dim3(16, 16), 256, 0, stream>>>(Acomb, resd, orlt, sigt, orlT);
  gus_csa<<<1152, 256, 0, stream>>>(gus_bf, orlT, sigt, orlt, Zt);
  mfma_gemm_ks<<<dim3(16, 8, 2), 256, 0, stream>>>(wdown_bf, Zt, rawP, 1024);
  norm_down2p<<<256, 256, 0, stream>>>(rawP, Zt2);
  mfma_gemm_ks<<<dim3(16, 8, 2), 256, 0, stream>>>(wfuse_bf, Zt2, rawP, 1024);
  norm_leaky2p<<<256, 256, 0, stream>>>(rawP, (float*)d_out);
}